// Round 5
// baseline (178.903 us; speedup 1.0000x reference)
//
#include <hip/hip_runtime.h>

// DynamicFilter_79448305041858
//
// Key observation: the reference applies softmax over a size-1 axis
// (df[:, :, None, None], axis=-2), which yields exactly 1.0 everywhere.
// Hence the dynamically generated filter is all-ones and the op reduces to
// an unweighted 3x3 box SUM with reflect padding:
//   out[n,c,y,x] = sum_{dy,dx in {-1,0,1}} x[n,c, r(y+dy), r(x+dx)]
// with reflect index r(-1)=1, r(H)=H-2 (jnp.pad mode="reflect").
// All GEMM/sigmoid/BN inputs (w_conv, w_gate, bn_*) are dead.

#define HH 56
#define WW 56
#define PLANE (HH * WW)   // 3136 floats = 12544 bytes per (n,c) plane

__global__ __launch_bounds__(256)
void box3x3_reflect_kernel(const float* __restrict__ x, float* __restrict__ out) {
    __shared__ float tile[PLANE];

    const long long plane = blockIdx.x;
    const float* __restrict__ xp = x + plane * PLANE;
    float* __restrict__ op = out + plane * PLANE;

    // Stage the 56x56 plane into LDS with coalesced float4 loads.
    // Plane base offset is plane*12544 bytes -> 16B aligned.
    const float4* __restrict__ x4 = reinterpret_cast<const float4*>(xp);
    float4* t4 = reinterpret_cast<float4*>(tile);
    #pragma unroll
    for (int i = threadIdx.x; i < PLANE / 4; i += 256)
        t4[i] = x4[i];
    __syncthreads();

    // Each thread computes pixels idx, idx+256, ... (13 iterations, last partial).
    for (int idx = threadIdx.x; idx < PLANE; idx += 256) {
        const int y = idx / WW;             // constant divisor -> magic multiply
        const int xc = idx - y * WW;

        const int ym = (y == 0)      ? 1      : y - 1;
        const int yp = (y == HH - 1) ? HH - 2 : y + 1;
        const int xm = (xc == 0)      ? 1      : xc - 1;
        const int xq = (xc == WW - 1) ? WW - 2 : xc + 1;

        const float* r0 = tile + ym * WW;
        const float* r1 = tile + y  * WW;
        const float* r2 = tile + yp * WW;

        const float s = r0[xm] + r0[xc] + r0[xq]
                      + r1[xm] + r1[xc] + r1[xq]
                      + r2[xm] + r2[xc] + r2[xq];
        op[idx] = s;
    }
}

extern "C" void kernel_launch(void* const* d_in, const int* in_sizes, int n_in,
                              void* d_out, int out_size, void* d_ws, size_t ws_size,
                              hipStream_t stream) {
    const float* x = (const float*)d_in[0];   // [16, 384, 56, 56] fp32
    float* out = (float*)d_out;               // same shape

    const int n_planes = out_size / PLANE;    // 16*384 = 6144
    box3x3_reflect_kernel<<<n_planes, 256, 0, stream>>>(x, out);
}

// Round 8
// 176.788 us; speedup vs baseline: 1.0120x; 1.0120x over previous
//
#include <hip/hip_runtime.h>

// DynamicFilter_79448305041858
//
// softmax over a size-1 axis == 1.0 -> the dynamic filter is all-ones and the
// op reduces to an unweighted 3x3 reflect-padded box SUM per (n,c) plane:
//   out[n,c,y,x] = sum_{dy,dx in {-1,0,1}} x[n,c, r(y+dy), r(x+dx)]
// (r(-1)=1, r(56)=54). w_conv/w_gate/bn_* are dead inputs. Verified R5
// (absmax 3.1e-2 << 4.5e-1 threshold).
//
// R5 post-mortem: 50us, LDS-issue-bound (9x ds_read_b32 per pixel ~= 61K
// cyc/CU on the per-CU LDS pipe; HBM only 29% of peak). R6: 4 px/thread via
// ds_read_b128 + 2 edge b32 per row -> 9 LDS instrs per 4 px (4x fewer),
// vertical-first adds (20 adds/4px).

#define HH 56
#define WW 56
#define PLANE (HH * WW)   // 3136 floats = 12544 B per (n,c) plane
#define NF4 (PLANE / 4)   // 784 float4 groups, 14 per row

__global__ __launch_bounds__(256)
void box3x3_reflect_v2(const float* __restrict__ x, float* __restrict__ out) {
    __shared__ float tile[PLANE];

    const long long plane = blockIdx.x;
    const float* __restrict__ xp = x + plane * (long long)PLANE;
    float* __restrict__ op = out + plane * (long long)PLANE;

    // Stage the plane into LDS with coalesced float4 loads (16B-aligned base).
    const float4* __restrict__ x4 = reinterpret_cast<const float4*>(xp);
    float4* t4 = reinterpret_cast<float4*>(tile);
    #pragma unroll
    for (int i = threadIdx.x; i < NF4; i += 256)
        t4[i] = x4[i];
    __syncthreads();

    // Each thread computes 4 horizontally-consecutive output pixels.
    // q is row-major over float4 groups -> stores are contiguous across lanes.
    for (int q = threadIdx.x; q < NF4; q += 256) {
        const int y = q / 14;            // constant divisor -> magic multiply
        const int c = (q - y * 14) * 4;  // column of first pixel (0,4,...,52)

        const int ym = (y == 0)      ? 1      : y - 1;
        const int yp = (y == HH - 1) ? HH - 2 : y + 1;
        const int li = (c == 0)      ? 1      : c - 1;   // reflected left col
        const int ri = (c == WW - 4) ? WW - 2 : c + 4;   // reflected right col

        const float* r0 = tile + ym * WW;
        const float* r1 = tile + y  * WW;
        const float* r2 = tile + yp * WW;

        // 3 aligned 16B reads + 6 scalar edge reads (ds_read_b128 / b32).
        const float4 a = *reinterpret_cast<const float4*>(r0 + c);
        const float4 b = *reinterpret_cast<const float4*>(r1 + c);
        const float4 d = *reinterpret_cast<const float4*>(r2 + c);
        const float l0 = r0[li], l1 = r1[li], l2 = r2[li];
        const float e0 = r0[ri], e1 = r1[ri], e2 = r2[ri];

        // Vertical sums first (12 adds), then horizontal window (8 adds).
        float4 v;
        v.x = a.x + b.x + d.x;
        v.y = a.y + b.y + d.y;
        v.z = a.z + b.z + d.z;
        v.w = a.w + b.w + d.w;
        const float lv = l0 + l1 + l2;
        const float rv = e0 + e1 + e2;

        float4 o;
        o.x = lv  + v.x + v.y;
        o.y = v.x + v.y + v.z;
        o.z = v.y + v.z + v.w;
        o.w = v.z + v.w + rv;

        *reinterpret_cast<float4*>(op + y * WW + c) = o;
    }
}

extern "C" void kernel_launch(void* const* d_in, const int* in_sizes, int n_in,
                              void* d_out, int out_size, void* d_ws, size_t ws_size,
                              hipStream_t stream) {
    const float* x = (const float*)d_in[0];   // [16, 384, 56, 56] fp32
    float* out = (float*)d_out;               // same shape

    const int n_planes = out_size / PLANE;    // 16*384 = 6144
    box3x3_reflect_v2<<<n_planes, 256, 0, stream>>>(x, out);
}